// Round 17
// baseline (306.294 us; speedup 1.0000x reference)
//
#include <hip/hip_runtime.h>

#define B_  2
#define S_  2048
#define D_  2048
#define H_  16
#define HD_ 128

typedef float  f32x4  __attribute__((ext_vector_type(4)));
typedef float  f32x16 __attribute__((ext_vector_type(16)));
typedef __bf16 bf16x8 __attribute__((ext_vector_type(8)));
typedef unsigned int u32;

__device__ __forceinline__ void gl16(const void* g, void* l) {
  __builtin_amdgcn_global_load_lds(
      (const __attribute__((address_space(1))) unsigned int*)g,
      (__attribute__((address_space(3))) unsigned int*)l, 16, 0, 0);
}

__device__ __forceinline__ ushort f2bf(float f) {
  union { float f; unsigned u; } v; v.f = f;
  unsigned r = v.u + 0x7FFFu + ((v.u >> 16) & 1u);   // RNE
  return (ushort)(r >> 16);
}
__device__ __forceinline__ float bf2f(ushort b) {
  union { unsigned u; float f; } v; v.u = ((unsigned)b) << 16;
  return v.f;
}
__device__ __forceinline__ f32x4 fzero() {
  f32x4 v; v[0] = 0.f; v[1] = 0.f; v[2] = 0.f; v[3] = 0.f; return v;
}
// raw v_exp_f32: D = 2^S0
__device__ __forceinline__ float exp2x(float x) {
  return __builtin_amdgcn_exp2f(x);
}

// ---------------- fused fp32 -> bf16 convert (all 5 inputs, 1 dispatch) ----
// dest regions are contiguous in ws: xb(16M) wqb(8M) wkb(8M) wvb(8M) wob(8M)
__global__ void cvt_all(const float* __restrict__ x,  const float* __restrict__ wq,
                        const float* __restrict__ wk, const float* __restrict__ wv,
                        const float* __restrict__ wo, ushort* __restrict__ dst)
{
  int i = blockIdx.x * blockDim.x + threadIdx.x;      // float4 index, 6291456 total
  if (i >= 6291456) return;
  const float* s;
  int t = i - 2097152;
  if (t < 0)             { s = x;  t = i; }
  else if (t < 1048576)  { s = wq; }
  else if (t < 2097152)  { s = wk; t -= 1048576; }
  else if (t < 3145728)  { s = wv; t -= 2097152; }
  else                   { s = wo; t -= 3145728; }
  float4 v = ((const float4*)s)[t];
  ((ushort4*)dst)[i] = make_ushort4(f2bf(v.x), f2bf(v.y), f2bf(v.z), f2bf(v.w));
}

// ---------------- MFMA GEMM (m97 recipe, HW-verified) ----------------
// C[m,n] = sum_k A[m,k]*B[n,k], both bf16 row-major (K fast).
// MODE 0: fp32 row-major MxN -> (float*)
// MODE 4: fused QKV scatter, N=6144: which=n>>11 -> 0:Q (B,H,S,HD),
//         1:K (B,H,S,HD), 2:V^T (B,H,HD,S); dest base Cp=Qb, +8388608/which.
template<int MODE>
__global__ __launch_bounds__(256, 2)
void gemm_bt(const ushort* __restrict__ A, const ushort* __restrict__ Bp,
             void* __restrict__ Cp, int M, int N, int K)
{
  __shared__ __align__(16) ushort lds[2][2][128 * 32];
  const int tid  = threadIdx.x;
  const int wave = tid >> 6, lane = tid & 63;
  const int qt = lane >> 4, ln = lane & 15;
  const int wr = wave >> 1, wc = wave & 1;
  const int bm = blockIdx.x * 128, bn = blockIdx.y * 128;

  f32x4 acc[4][4];
#pragma unroll
  for (int a = 0; a < 4; ++a)
#pragma unroll
    for (int b = 0; b < 4; ++b) acc[a][b] = fzero();

  auto stage = [&](int buf, int kt) {
#pragma unroll
    for (int it = 0; it < 2; ++it) {
      int c = it * 256 + tid;
      int row = c >> 2, ch = c & 3;
      int chs = ch ^ ((row >> 1) & 3);
      gl16(A  + (size_t)(bm + row) * K + kt + chs * 8,
           (void*)&lds[buf][0][(it * 256 + wave * 64) * 8]);
      gl16(Bp + (size_t)(bn + row) * K + kt + chs * 8,
           (void*)&lds[buf][1][(it * 256 + wave * 64) * 8]);
    }
  };

  const int nk = K >> 5;
  stage(0, 0);
  int cur = 0;
  for (int kt = 0; kt < nk; ++kt) {
    __syncthreads();                      // drains vmcnt -> buf[cur] staged
    if (kt + 1 < nk) stage(cur ^ 1, (kt + 1) << 5);
    bf16x8 af[4], bfr[4];
#pragma unroll
    for (int mf = 0; mf < 4; ++mf) {
      int row = wr * 64 + mf * 16 + ln;
      int sl = qt ^ ((row >> 1) & 3);
      af[mf] = *(const bf16x8*)&lds[cur][0][row * 32 + sl * 8];
    }
#pragma unroll
    for (int nf = 0; nf < 4; ++nf) {
      int row = wc * 64 + nf * 16 + ln;
      int sl = qt ^ ((row >> 1) & 3);
      bfr[nf] = *(const bf16x8*)&lds[cur][1][row * 32 + sl * 8];
    }
#pragma unroll
    for (int mf = 0; mf < 4; ++mf)
#pragma unroll
      for (int nf = 0; nf < 4; ++nf)
        acc[mf][nf] = __builtin_amdgcn_mfma_f32_16x16x32_bf16(
            af[mf], bfr[nf], acc[mf][nf], 0, 0, 0);
    cur ^= 1;
  }

  // epilogue: C/D layout col=lane&15, row=(lane>>4)*4+reg  [HW-verified]
#pragma unroll
  for (int mf = 0; mf < 4; ++mf)
#pragma unroll
    for (int nf = 0; nf < 4; ++nf) {
      int m0 = bm + wr * 64 + mf * 16 + qt * 4;
      int n  = bn + wc * 64 + nf * 16 + ln;
#pragma unroll
      for (int i = 0; i < 4; ++i) {
        int m = m0 + i;
        if (MODE == 0) {
          ((float*)Cp)[(size_t)m * N + n] = acc[mf][nf][i];
        } else {
          int b = m >> 11, s = m & 2047;     // m = b*S + s
          int which = n >> 11;               // 0:Q 1:K 2:V
          int nn = n & 2047;
          int h = nn >> 7, d = nn & 127;
          size_t off = (size_t)which * 8388608;
          size_t idx = (which == 2)
              ? (((size_t)b * H_ + h) * HD_ + d) * S_ + s    // V^T (B,H,HD,S)
              : (((size_t)b * H_ + h) * S_ + s) * HD_ + d;   // Q,K (B,H,S,HD)
          ((ushort*)Cp)[off + idx] = f2bf(acc[mf][nf][i]);
        }
      }
    }
}

// ---------------- RoPE on Q,K bf16 in (B,H,S,HD), in place ----------------
__global__ void rope_qk(ushort* __restrict__ Q, ushort* __restrict__ Kt,
                        const float* __restrict__ cs, const float* __restrict__ sn)
{
  int t = blockIdx.x * 256 + threadIdx.x;   // 2 * B*H*S * 64 threads
  int d  = t & 63;
  int rr = t >> 6;                          // 0 .. 2*B*H*S-1
  int isk = rr >> 16;                       // B*H*S = 65536
  int bhs = rr & 65535;
  int s = bhs & 2047;
  int b = bhs >> 15;
  ushort* P = isk ? Kt : Q;
  size_t ro = (size_t)bhs * HD_;
  float q0 = bf2f(P[ro + d]), q1 = bf2f(P[ro + d + 64]);
  size_t ci = ((size_t)b * S_ + s) * HD_ + d;
  float c0 = cs[ci], s0 = sn[ci], c1 = cs[ci + 64], s1 = sn[ci + 64];
  P[ro + d]      = f2bf(q0 * c0 - q1 * s0);
  P[ro + d + 64] = f2bf(q1 * c1 + q0 * s1);
}

// ---------------- flash attention: 32x32 MFMA, rotation swizzles -----------
// grid (B*H, S/128), 256 thr = 4 waves x 32 q-rows. K dbuf, V single buffer.
// ROTATION swizzles (conflict-free, verified by quad arithmetic):
//   K [64 rows][16 ch]: slot = (g + (row>>1)) & 15   (quad=(row&1)*16+slot
//     bijective per 32-lane half; cross-half 2-way = free per m136)
//   V [128 rows][8 ch]: slot = (g + (d>>2)) & 7      (quad=(d&3)*8+slot)
// Stage side uses inverse: g = (slot - (row>>1)) & 15 etc. (rule #21).
// QK^T = mfma_32x32x16(K,Q): thread owns q=lane&31; P in regs; PV A-frags
// via 2 shfl_xor(32) each; accO q=(reg&3)+8*(reg>>2)+4*hi, d=dblk*32+ln32.
__global__ __launch_bounds__(256, 2)
void flash(const ushort* __restrict__ Q, const ushort* __restrict__ Kk,
           const ushort* __restrict__ VT, const float* __restrict__ mask,
           ushort* __restrict__ O)
{
  __shared__ __align__(16) ushort kt_s[2][64 * 128];
  __shared__ __align__(16) ushort vt_s[128 * 64];

  const int tid = threadIdx.x;
  const int wave = tid >> 6, lane = tid & 63;
  const int ln32 = lane & 31, hi = lane >> 5;
  const int bh = blockIdx.x, b = bh >> 4, h = bh & 15;
  const size_t base  = (size_t)bh * S_ * HD_;
  const size_t baseT = (size_t)bh * HD_ * S_;
  const int q0 = blockIdx.y * 128 + wave * 32;
  const float L2E = 1.4426950408889634f;
  const float scale2 = 0.08838834764831845f * L2E;

  // Q fragments: B-operand col=lane&31=q, k = hd*16 + hi*8 + j
  bf16x8 qf[8];
  {
    const ushort* qrow = Q + base + (size_t)(q0 + ln32) * HD_;
#pragma unroll
    for (int hd = 0; hd < 8; ++hd)
      qf[hd] = *(const bf16x8*)(qrow + hd * 16 + hi * 8);
  }

  f32x16 accO[4];
#pragma unroll
  for (int dblk = 0; dblk < 4; ++dblk)
#pragma unroll
    for (int i = 0; i < 16; ++i) accO[dblk][i] = 0.f;
  float mrun = -1e30f;     // per-thread, q = ln32 (pair-synced via shfl)
  float lrun = 0.f;        // per-thread half-row partial

  auto stageK = [&](int buf, int k0) {
#pragma unroll
    for (int it = 0; it < 4; ++it) {         // 1024 chunks, 256 thr
      int c = it * 256 + tid;
      int row = c >> 4, sl = c & 15;
      int chs = (sl - (row >> 1)) & 15;      // inverse rotation
      gl16(Kk + base + (size_t)(k0 + row) * HD_ + chs * 8,
           (void*)&kt_s[buf][(it * 256 + wave * 64) * 8]);
    }
  };
  auto stageV = [&](int k0) {
#pragma unroll
    for (int it = 0; it < 4; ++it) {         // 1024 chunks
      int c = it * 256 + tid;
      int d = c >> 3, sl = c & 7;
      int chs = (sl - (d >> 2)) & 7;         // inverse rotation
      gl16(VT + baseT + (size_t)d * S_ + k0 + chs * 8,
           (void*)&vt_s[(it * 256 + wave * 64) * 8]);
    }
  };

  stageK(0, 0);
  stageV(0);
  int cur = 0;
  for (int k0 = 0; k0 < S_; k0 += 64) {
    __syncthreads();                         // K[cur] + V staged; prev reads done
    if (k0 + 64 < S_) stageK(cur ^ 1, k0 + 64);   // flies under compute

    // QK^T swapped: sc[kblk] = S^T[k = kblk*32+crow][q = ln32]
    f32x16 sc[2];
    __builtin_amdgcn_s_setprio(1);
#pragma unroll
    for (int kblk = 0; kblk < 2; ++kblk) {
      f32x16 a;
#pragma unroll
      for (int i = 0; i < 16; ++i) a[i] = 0.f;
      int row = kblk * 32 + ln32;
#pragma unroll
      for (int hd = 0; hd < 8; ++hd) {
        int sl = (hd * 2 + hi + (row >> 1)) & 15;    // rotation
        bf16x8 kf = *(const bf16x8*)&kt_s[cur][row * 128 + sl * 8];
        a = __builtin_amdgcn_mfma_f32_32x32x16_bf16(kf, qf[hd], a, 0, 0, 0);
      }
      sc[kblk] = a;
    }
    __builtin_amdgcn_s_setprio(0);

    // scale + mask (log2 domain); k = kblk*32 + 8g + 4hi + j for reg=4g+j
    float sv[2][16];
#pragma unroll
    for (int kblk = 0; kblk < 2; ++kblk)
#pragma unroll
      for (int g = 0; g < 4; ++g) {
        float4 mk = *(const float4*)&mask[(size_t)b * S_ + k0 + kblk * 32 + g * 8 + hi * 4];
        sv[kblk][g * 4 + 0] = sc[kblk][g * 4 + 0] * scale2 + mk.x * L2E;
        sv[kblk][g * 4 + 1] = sc[kblk][g * 4 + 1] * scale2 + mk.y * L2E;
        sv[kblk][g * 4 + 2] = sc[kblk][g * 4 + 2] * scale2 + mk.z * L2E;
        sv[kblk][g * 4 + 3] = sc[kblk][g * 4 + 3] * scale2 + mk.w * L2E;
      }

    // row max: 31 in-thread fmax + 1 cross-lane hop (pair lane^32)
    float m = sv[0][0];
#pragma unroll
    for (int kblk = 0; kblk < 2; ++kblk)
#pragma unroll
      for (int i = 0; i < 16; ++i) m = fmaxf(m, sv[kblk][i]);
    m = fmaxf(m, __shfl_xor(m, 32));

    // defer-max rescale (THR=8, exp2 domain)
    if (__any(m > mrun + 8.f)) {
      float mn = fmaxf(mrun, m);
      float fsc = exp2x(mrun - mn);
      mrun = mn;
      lrun *= fsc;
      float fq[16];
#pragma unroll
      for (int g = 0; g < 4; ++g)
#pragma unroll
        for (int j = 0; j < 4; ++j)
          fq[g * 4 + j] = __shfl(fsc, j + 8 * g + 4 * hi);
#pragma unroll
      for (int dblk = 0; dblk < 4; ++dblk)
#pragma unroll
        for (int i = 0; i < 16; ++i) accO[dblk][i] *= fq[i];
    }

    // P = exp2(sv - mrun) -> bf16 in regs; per-thread partial sum
    float tsum = 0.f;
    ushort pb[2][16];
#pragma unroll
    for (int kblk = 0; kblk < 2; ++kblk)
#pragma unroll
      for (int i = 0; i < 16; ++i) {
        float p = exp2x(sv[kblk][i] - mrun);
        __bf16 pq = (__bf16)p;               // HW cvt, RNE
        union { __bf16 b; ushort s; } cc; cc.b = pq;
        pb[kblk][i] = cc.s;
        tsum += (float)pq;                   // sum QUANTIZED P -> exact norm
      }
    lrun += tsum;

    // assemble PV A-frags in-register (2 shfl_xor(32) per frag pair)
    bf16x8 pa[4];
#pragma unroll
    for (int kblk = 0; kblk < 2; ++kblk) {
      u32 pk0[4], pk1[4];
#pragma unroll
      for (int t = 0; t < 4; ++t) {
        pk0[t] = (u32)pb[kblk][4 * t]     | ((u32)pb[kblk][4 * t + 1] << 16);
        pk1[t] = (u32)pb[kblk][4 * t + 2] | ((u32)pb[kblk][4 * t + 3] << 16);
      }
#pragma unroll
      for (int c = 0; c < 2; ++c) {
        u32 a0 = pk0[2 * c],     a1 = pk1[2 * c];       // t' = 2c
        u32 b0 = pk0[2 * c + 1], b1 = pk1[2 * c + 1];   // t' = 2c+1
        u32 s0 = hi ? a0 : b0,   s1 = hi ? a1 : b1;     // partner needs t'=(1-hi)+2c
        u32 r0 = (u32)__shfl_xor((int)s0, 32);
        u32 r1 = (u32)__shfl_xor((int)s1, 32);
        u32 o0 = hi ? b0 : a0,   o1 = hi ? b1 : a1;     // own t' = hi+2c
        u32 w[4];
        w[0] = hi ? r0 : o0;  w[1] = hi ? r1 : o1;      // quad(t',0)
        w[2] = hi ? o0 : r0;  w[3] = hi ? o1 : r1;      // quad(t',1)
        pa[kblk * 2 + c] = *(bf16x8*)w;
      }
    }

    // PV: accO[q 32][d 128] += P * V
    __builtin_amdgcn_s_setprio(1);
#pragma unroll
    for (int kk = 0; kk < 4; ++kk)
#pragma unroll
      for (int dblk = 0; dblk < 4; ++dblk) {
        int d = dblk * 32 + ln32;
        int sl = (kk * 2 + hi + (d >> 2)) & 7;          // rotation
        bf16x8 vf = *(const bf16x8*)&vt_s[d * 64 + sl * 8];
        accO[dblk] = __builtin_amdgcn_mfma_f32_32x32x16_bf16(pa[kk], vf, accO[dblk], 0, 0, 0);
      }
    __builtin_amdgcn_s_setprio(0);

    __syncthreads();                         // all waves done reading V
    if (k0 + 64 < S_) stageV(k0 + 64);       // covered by co-resident block
    cur ^= 1;
  }

  // epilogue: pair-reduce lrun, fetch inv per accO row, write O (B,S,D) bf16
  lrun += __shfl_xor(lrun, 32);
  float inv_own = 1.f / lrun;
  float invv[16];
#pragma unroll
  for (int g = 0; g < 4; ++g)
#pragma unroll
    for (int j = 0; j < 4; ++j)
      invv[g * 4 + j] = __shfl(inv_own, j + 8 * g + 4 * hi);
#pragma unroll
  for (int dblk = 0; dblk < 4; ++dblk)
#pragma unroll
    for (int g = 0; g < 4; ++g)
#pragma unroll
      for (int j = 0; j < 4; ++j) {
        int q = j + 8 * g + 4 * hi;
        size_t idx = ((size_t)b * S_ + q0 + q) * D_ + h * HD_ + dblk * 32 + ln32;
        O[idx] = f2bf(accO[dblk][g * 4 + j] * invv[g * 4 + j]);
      }
}

// ---------------- launcher ----------------
extern "C" void kernel_launch(void* const* d_in, const int* in_sizes, int n_in,
                              void* d_out, int out_size, void* d_ws, size_t ws_size,
                              hipStream_t stream)
{
  if (n_in != 8) return;
  if (in_sizes[0] != 8388608) return;       // x  (B,S,D)
  if (in_sizes[3] != 4096)    return;       // mask (B,S)
  if (out_size != 8388608) return;
  if (ws_size < (size_t)96 * 1024 * 1024) return;

  const float* x    = (const float*)d_in[0];
  const float* cosb = (const float*)d_in[1];
  const float* sinb = (const float*)d_in[2];
  const float* mask = (const float*)d_in[3];
  const float* wq   = (const float*)d_in[4];
  const float* wk   = (const float*)d_in[5];
  const float* wv   = (const float*)d_in[6];
  const float* wo   = (const float*)d_in[7];

  char* ws = (char*)d_ws;
  // layout (MB): xb 0..16 | wqkv 16..40 (wq|wk|wv contiguous) | wob 40..48 |
  //              Qb 48..64 | Kb 64..80 | VTb 80..96
  ushort* xb   = (ushort*)(ws);
  ushort* wqkv = (ushort*)(ws + 16777216);
  ushort* wob  = (ushort*)(ws + 41943040);
  ushort* Qb   = (ushort*)(ws + 50331648);
  ushort* Kb   = (ushort*)(ws + 67108864);
  ushort* VTb  = (ushort*)(ws + 83886080);
  ushort* AOb  = xb;   // reuse: x_bf16 dead after QKV GEMM

  // 1 dispatch: convert x + wq + wk + wv + wo into contiguous ws[0..48MB)
  cvt_all<<<24576, 256, 0, stream>>>(x, wq, wk, wv, wo, xb);

  // fused QKV projection: one GEMM, N=6144; epilogue routes to Qb/Kb/VTb
  gemm_bt<4><<<dim3(32, 48), 256, 0, stream>>>(xb, wqkv, Qb, 4096, 6144, 2048);

  rope_qk<<<32768, 256, 0, stream>>>(Qb, Kb, cosb, sinb);

  flash<<<dim3(32, 16), 256, 0, stream>>>(Qb, Kb, VTb, mask, AOb);

  gemm_bt<0><<<dim3(32, 16), 256, 0, stream>>>(AOb, wob, d_out, 4096, 2048, 2048);
}

// Round 18
// 299.637 us; speedup vs baseline: 1.0222x; 1.0222x over previous
//
#include <hip/hip_runtime.h>

#define B_  2
#define S_  2048
#define D_  2048
#define H_  16
#define HD_ 128

typedef float  f32x4  __attribute__((ext_vector_type(4)));
typedef float  f32x16 __attribute__((ext_vector_type(16)));
typedef __bf16 bf16x8 __attribute__((ext_vector_type(8)));
typedef unsigned int u32;

__device__ __forceinline__ void gl16(const void* g, void* l) {
  __builtin_amdgcn_global_load_lds(
      (const __attribute__((address_space(1))) unsigned int*)g,
      (__attribute__((address_space(3))) unsigned int*)l, 16, 0, 0);
}

__device__ __forceinline__ ushort f2bf(float f) {
  union { float f; unsigned u; } v; v.f = f;
  unsigned r = v.u + 0x7FFFu + ((v.u >> 16) & 1u);   // RNE
  return (ushort)(r >> 16);
}
__device__ __forceinline__ float bf2f(ushort b) {
  union { unsigned u; float f; } v; v.u = ((unsigned)b) << 16;
  return v.f;
}
__device__ __forceinline__ f32x4 fzero() {
  f32x4 v; v[0] = 0.f; v[1] = 0.f; v[2] = 0.f; v[3] = 0.f; return v;
}
// raw v_exp_f32: D = 2^S0
__device__ __forceinline__ float exp2x(float x) {
  return __builtin_amdgcn_exp2f(x);
}

// ---------------- fused fp32 -> bf16 convert (all 5 inputs, 1 dispatch) ----
// dest regions are contiguous in ws: xb(16M) wqb(8M) wkb(8M) wvb(8M) wob(8M)
__global__ void cvt_all(const float* __restrict__ x,  const float* __restrict__ wq,
                        const float* __restrict__ wk, const float* __restrict__ wv,
                        const float* __restrict__ wo, ushort* __restrict__ dst)
{
  int i = blockIdx.x * blockDim.x + threadIdx.x;      // float4 index, 6291456 total
  if (i >= 6291456) return;
  const float* s;
  int t = i - 2097152;
  if (t < 0)             { s = x;  t = i; }
  else if (t < 1048576)  { s = wq; }
  else if (t < 2097152)  { s = wk; t -= 1048576; }
  else if (t < 3145728)  { s = wv; t -= 2097152; }
  else                   { s = wo; t -= 3145728; }
  float4 v = ((const float4*)s)[t];
  ((ushort4*)dst)[i] = make_ushort4(f2bf(v.x), f2bf(v.y), f2bf(v.z), f2bf(v.w));
}

// ---------------- MFMA GEMM (m97 recipe, HW-verified) ----------------
// C[m,n] = sum_k A[m,k]*B[n,k], both bf16 row-major (K fast). N=2048 per
// dispatch keeps A+B = 24MB < 32MB aggregate L2 (R17 lesson: fused N=6144
// thrashed L2, 725 TF vs ~950).
// MODE 0: fp32 row-major MxN -> (float*)
// MODE 1: bf16 scatter (B,H,S,HD) -> (ushort*)
// MODE 3: bf16 scatter (B,H,HD,S) -> (ushort*)   (transposed V)
template<int MODE>
__global__ __launch_bounds__(256, 2)
void gemm_bt(const ushort* __restrict__ A, const ushort* __restrict__ Bp,
             void* __restrict__ Cp, int M, int N, int K)
{
  __shared__ __align__(16) ushort lds[2][2][128 * 32];
  const int tid  = threadIdx.x;
  const int wave = tid >> 6, lane = tid & 63;
  const int qt = lane >> 4, ln = lane & 15;
  const int wr = wave >> 1, wc = wave & 1;
  const int bm = blockIdx.x * 128, bn = blockIdx.y * 128;

  f32x4 acc[4][4];
#pragma unroll
  for (int a = 0; a < 4; ++a)
#pragma unroll
    for (int b = 0; b < 4; ++b) acc[a][b] = fzero();

  auto stage = [&](int buf, int kt) {
#pragma unroll
    for (int it = 0; it < 2; ++it) {
      int c = it * 256 + tid;
      int row = c >> 2, ch = c & 3;
      int chs = ch ^ ((row >> 1) & 3);
      gl16(A  + (size_t)(bm + row) * K + kt + chs * 8,
           (void*)&lds[buf][0][(it * 256 + wave * 64) * 8]);
      gl16(Bp + (size_t)(bn + row) * K + kt + chs * 8,
           (void*)&lds[buf][1][(it * 256 + wave * 64) * 8]);
    }
  };

  const int nk = K >> 5;
  stage(0, 0);
  int cur = 0;
  for (int kt = 0; kt < nk; ++kt) {
    __syncthreads();                      // drains vmcnt -> buf[cur] staged
    if (kt + 1 < nk) stage(cur ^ 1, (kt + 1) << 5);
    bf16x8 af[4], bfr[4];
#pragma unroll
    for (int mf = 0; mf < 4; ++mf) {
      int row = wr * 64 + mf * 16 + ln;
      int sl = qt ^ ((row >> 1) & 3);
      af[mf] = *(const bf16x8*)&lds[cur][0][row * 32 + sl * 8];
    }
#pragma unroll
    for (int nf = 0; nf < 4; ++nf) {
      int row = wc * 64 + nf * 16 + ln;
      int sl = qt ^ ((row >> 1) & 3);
      bfr[nf] = *(const bf16x8*)&lds[cur][1][row * 32 + sl * 8];
    }
#pragma unroll
    for (int mf = 0; mf < 4; ++mf)
#pragma unroll
      for (int nf = 0; nf < 4; ++nf)
        acc[mf][nf] = __builtin_amdgcn_mfma_f32_16x16x32_bf16(
            af[mf], bfr[nf], acc[mf][nf], 0, 0, 0);
    cur ^= 1;
  }

  // epilogue: C/D layout col=lane&15, row=(lane>>4)*4+reg  [HW-verified]
#pragma unroll
  for (int mf = 0; mf < 4; ++mf)
#pragma unroll
    for (int nf = 0; nf < 4; ++nf) {
      int m0 = bm + wr * 64 + mf * 16 + qt * 4;
      int n  = bn + wc * 64 + nf * 16 + ln;
#pragma unroll
      for (int i = 0; i < 4; ++i) {
        int m = m0 + i;
        if (MODE == 0) {
          ((float*)Cp)[(size_t)m * N + n] = acc[mf][nf][i];
        } else {
          int b = m >> 11, s = m & 2047;     // m = b*S + s
          int h = n >> 7,  d = n & 127;      // n = h*HD + d
          if (MODE == 1)
            ((ushort*)Cp)[(((size_t)b * H_ + h) * S_ + s) * HD_ + d] = f2bf(acc[mf][nf][i]);
          else
            ((ushort*)Cp)[(((size_t)b * H_ + h) * HD_ + d) * S_ + s] = f2bf(acc[mf][nf][i]);
        }
      }
    }
}

// ---------------- RoPE on Q,K bf16 in (B,H,S,HD), in place ----------------
__global__ void rope_qk(ushort* __restrict__ Q, ushort* __restrict__ Kt,
                        const float* __restrict__ cs, const float* __restrict__ sn)
{
  int t = blockIdx.x * 256 + threadIdx.x;   // 2 * B*H*S * 64 threads
  int d  = t & 63;
  int rr = t >> 6;                          // 0 .. 2*B*H*S-1
  int isk = rr >> 16;                       // B*H*S = 65536
  int bhs = rr & 65535;
  int s = bhs & 2047;
  int b = bhs >> 15;
  ushort* P = isk ? Kt : Q;
  size_t ro = (size_t)bhs * HD_;
  float q0 = bf2f(P[ro + d]), q1 = bf2f(P[ro + d + 64]);
  size_t ci = ((size_t)b * S_ + s) * HD_ + d;
  float c0 = cs[ci], s0 = sn[ci], c1 = cs[ci + 64], s1 = sn[ci + 64];
  P[ro + d]      = f2bf(q0 * c0 - q1 * s0);
  P[ro + d + 64] = f2bf(q1 * c1 + q0 * s1);
}

// ---------------- flash attention: 32x32 MFMA, rotation swizzles -----------
// grid (B*H, S/128), 256 thr = 4 waves x 32 q-rows. K dbuf, V single buffer.
// ROTATION swizzles (conflict-free, R17-verified: flash ~84us):
//   K [64 rows][16 ch]: slot = (g + (row>>1)) & 15
//   V [128 rows][8 ch]: slot = (g + (d>>2)) & 7
// Stage side uses inverse (rule #21).
// QK^T = mfma_32x32x16(K,Q): thread owns q=lane&31; P in regs; PV A-frags
// via 2 shfl_xor(32) each; accO q=(reg&3)+8*(reg>>2)+4*hi, d=dblk*32+ln32.
__global__ __launch_bounds__(256, 2)
void flash(const ushort* __restrict__ Q, const ushort* __restrict__ Kk,
           const ushort* __restrict__ VT, const float* __restrict__ mask,
           ushort* __restrict__ O)
{
  __shared__ __align__(16) ushort kt_s[2][64 * 128];
  __shared__ __align__(16) ushort vt_s[128 * 64];

  const int tid = threadIdx.x;
  const int wave = tid >> 6, lane = tid & 63;
  const int ln32 = lane & 31, hi = lane >> 5;
  const int bh = blockIdx.x, b = bh >> 4, h = bh & 15;
  const size_t base  = (size_t)bh * S_ * HD_;
  const size_t baseT = (size_t)bh * HD_ * S_;
  const int q0 = blockIdx.y * 128 + wave * 32;
  const float L2E = 1.4426950408889634f;
  const float scale2 = 0.08838834764831845f * L2E;

  // Q fragments: B-operand col=lane&31=q, k = hd*16 + hi*8 + j
  bf16x8 qf[8];
  {
    const ushort* qrow = Q + base + (size_t)(q0 + ln32) * HD_;
#pragma unroll
    for (int hd = 0; hd < 8; ++hd)
      qf[hd] = *(const bf16x8*)(qrow + hd * 16 + hi * 8);
  }

  f32x16 accO[4];
#pragma unroll
  for (int dblk = 0; dblk < 4; ++dblk)
#pragma unroll
    for (int i = 0; i < 16; ++i) accO[dblk][i] = 0.f;
  float mrun = -1e30f;     // per-thread, q = ln32 (pair-synced via shfl)
  float lrun = 0.f;        // per-thread half-row partial

  auto stageK = [&](int buf, int k0) {
#pragma unroll
    for (int it = 0; it < 4; ++it) {         // 1024 chunks, 256 thr
      int c = it * 256 + tid;
      int row = c >> 4, sl = c & 15;
      int chs = (sl - (row >> 1)) & 15;      // inverse rotation
      gl16(Kk + base + (size_t)(k0 + row) * HD_ + chs * 8,
           (void*)&kt_s[buf][(it * 256 + wave * 64) * 8]);
    }
  };
  auto stageV = [&](int k0) {
#pragma unroll
    for (int it = 0; it < 4; ++it) {         // 1024 chunks
      int c = it * 256 + tid;
      int d = c >> 3, sl = c & 7;
      int chs = (sl - (d >> 2)) & 7;         // inverse rotation
      gl16(VT + baseT + (size_t)d * S_ + k0 + chs * 8,
           (void*)&vt_s[(it * 256 + wave * 64) * 8]);
    }
  };

  stageK(0, 0);
  stageV(0);
  int cur = 0;
  for (int k0 = 0; k0 < S_; k0 += 64) {
    __syncthreads();                         // K[cur] + V staged; prev reads done
    if (k0 + 64 < S_) stageK(cur ^ 1, k0 + 64);   // flies under compute

    // QK^T swapped: sc[kblk] = S^T[k = kblk*32+crow][q = ln32]
    f32x16 sc[2];
    __builtin_amdgcn_s_setprio(1);
#pragma unroll
    for (int kblk = 0; kblk < 2; ++kblk) {
      f32x16 a;
#pragma unroll
      for (int i = 0; i < 16; ++i) a[i] = 0.f;
      int row = kblk * 32 + ln32;
#pragma unroll
      for (int hd = 0; hd < 8; ++hd) {
        int sl = (hd * 2 + hi + (row >> 1)) & 15;    // rotation
        bf16x8 kf = *(const bf16x8*)&kt_s[cur][row * 128 + sl * 8];
        a = __builtin_amdgcn_mfma_f32_32x32x16_bf16(kf, qf[hd], a, 0, 0, 0);
      }
      sc[kblk] = a;
    }
    __builtin_amdgcn_s_setprio(0);

    // scale + mask (log2 domain); k = kblk*32 + 8g + 4hi + j for reg=4g+j
    float sv[2][16];
#pragma unroll
    for (int kblk = 0; kblk < 2; ++kblk)
#pragma unroll
      for (int g = 0; g < 4; ++g) {
        float4 mk = *(const float4*)&mask[(size_t)b * S_ + k0 + kblk * 32 + g * 8 + hi * 4];
        sv[kblk][g * 4 + 0] = sc[kblk][g * 4 + 0] * scale2 + mk.x * L2E;
        sv[kblk][g * 4 + 1] = sc[kblk][g * 4 + 1] * scale2 + mk.y * L2E;
        sv[kblk][g * 4 + 2] = sc[kblk][g * 4 + 2] * scale2 + mk.z * L2E;
        sv[kblk][g * 4 + 3] = sc[kblk][g * 4 + 3] * scale2 + mk.w * L2E;
      }

    // row max: 31 in-thread fmax + 1 cross-lane hop (pair lane^32)
    float m = sv[0][0];
#pragma unroll
    for (int kblk = 0; kblk < 2; ++kblk)
#pragma unroll
      for (int i = 0; i < 16; ++i) m = fmaxf(m, sv[kblk][i]);
    m = fmaxf(m, __shfl_xor(m, 32));

    // defer-max rescale (THR=8, exp2 domain)
    if (__any(m > mrun + 8.f)) {
      float mn = fmaxf(mrun, m);
      float fsc = exp2x(mrun - mn);
      mrun = mn;
      lrun *= fsc;
      float fq[16];
#pragma unroll
      for (int g = 0; g < 4; ++g)
#pragma unroll
        for (int j = 0; j < 4; ++j)
          fq[g * 4 + j] = __shfl(fsc, j + 8 * g + 4 * hi);
#pragma unroll
      for (int dblk = 0; dblk < 4; ++dblk)
#pragma unroll
        for (int i = 0; i < 16; ++i) accO[dblk][i] *= fq[i];
    }

    // P = exp2(sv - mrun) -> bf16 in regs; per-thread partial sum
    float tsum = 0.f;
    ushort pb[2][16];
#pragma unroll
    for (int kblk = 0; kblk < 2; ++kblk)
#pragma unroll
      for (int i = 0; i < 16; ++i) {
        float p = exp2x(sv[kblk][i] - mrun);
        __bf16 pq = (__bf16)p;               // HW cvt, RNE
        union { __bf16 b; ushort s; } cc; cc.b = pq;
        pb[kblk][i] = cc.s;
        tsum += (float)pq;                   // sum QUANTIZED P -> exact norm
      }
    lrun += tsum;

    // assemble PV A-frags in-register (2 shfl_xor(32) per frag pair)
    bf16x8 pa[4];
#pragma unroll
    for (int kblk = 0; kblk < 2; ++kblk) {
      u32 pk0[4], pk1[4];
#pragma unroll
      for (int t = 0; t < 4; ++t) {
        pk0[t] = (u32)pb[kblk][4 * t]     | ((u32)pb[kblk][4 * t + 1] << 16);
        pk1[t] = (u32)pb[kblk][4 * t + 2] | ((u32)pb[kblk][4 * t + 3] << 16);
      }
#pragma unroll
      for (int c = 0; c < 2; ++c) {
        u32 a0 = pk0[2 * c],     a1 = pk1[2 * c];       // t' = 2c
        u32 b0 = pk0[2 * c + 1], b1 = pk1[2 * c + 1];   // t' = 2c+1
        u32 s0 = hi ? a0 : b0,   s1 = hi ? a1 : b1;     // partner needs t'=(1-hi)+2c
        u32 r0 = (u32)__shfl_xor((int)s0, 32);
        u32 r1 = (u32)__shfl_xor((int)s1, 32);
        u32 o0 = hi ? b0 : a0,   o1 = hi ? b1 : a1;     // own t' = hi+2c
        u32 w[4];
        w[0] = hi ? r0 : o0;  w[1] = hi ? r1 : o1;      // quad(t',0)
        w[2] = hi ? o0 : r0;  w[3] = hi ? o1 : r1;      // quad(t',1)
        pa[kblk * 2 + c] = *(bf16x8*)w;
      }
    }

    // PV: accO[q 32][d 128] += P * V
    __builtin_amdgcn_s_setprio(1);
#pragma unroll
    for (int kk = 0; kk < 4; ++kk)
#pragma unroll
      for (int dblk = 0; dblk < 4; ++dblk) {
        int d = dblk * 32 + ln32;
        int sl = (kk * 2 + hi + (d >> 2)) & 7;          // rotation
        bf16x8 vf = *(const bf16x8*)&vt_s[d * 64 + sl * 8];
        accO[dblk] = __builtin_amdgcn_mfma_f32_32x32x16_bf16(pa[kk], vf, accO[dblk], 0, 0, 0);
      }
    __builtin_amdgcn_s_setprio(0);

    __syncthreads();                         // all waves done reading V
    if (k0 + 64 < S_) stageV(k0 + 64);       // covered by co-resident block
    cur ^= 1;
  }

  // epilogue: pair-reduce lrun, fetch inv per accO row, write O (B,S,D) bf16
  lrun += __shfl_xor(lrun, 32);
  float inv_own = 1.f / lrun;
  float invv[16];
#pragma unroll
  for (int g = 0; g < 4; ++g)
#pragma unroll
    for (int j = 0; j < 4; ++j)
      invv[g * 4 + j] = __shfl(inv_own, j + 8 * g + 4 * hi);
#pragma unroll
  for (int dblk = 0; dblk < 4; ++dblk)
#pragma unroll
    for (int g = 0; g < 4; ++g)
#pragma unroll
      for (int j = 0; j < 4; ++j) {
        int q = j + 8 * g + 4 * hi;
        size_t idx = ((size_t)b * S_ + q0 + q) * D_ + h * HD_ + dblk * 32 + ln32;
        O[idx] = f2bf(accO[dblk][g * 4 + j] * invv[g * 4 + j]);
      }
}

// ---------------- launcher ----------------
extern "C" void kernel_launch(void* const* d_in, const int* in_sizes, int n_in,
                              void* d_out, int out_size, void* d_ws, size_t ws_size,
                              hipStream_t stream)
{
  if (n_in != 8) return;
  if (in_sizes[0] != 8388608) return;       // x  (B,S,D)
  if (in_sizes[3] != 4096)    return;       // mask (B,S)
  if (out_size != 8388608) return;
  if (ws_size < (size_t)96 * 1024 * 1024) return;

  const float* x    = (const float*)d_in[0];
  const float* cosb = (const float*)d_in[1];
  const float* sinb = (const float*)d_in[2];
  const float* mask = (const float*)d_in[3];
  const float* wq   = (const float*)d_in[4];
  const float* wk   = (const float*)d_in[5];
  const float* wv   = (const float*)d_in[6];
  const float* wo   = (const float*)d_in[7];

  char* ws = (char*)d_ws;
  // layout (MB): xb 0..16 | wqb 16..24 | wkb 24..32 | wvb 32..40 | wob 40..48 |
  //              Qb 48..64 | Kb 64..80 | VTb 80..96
  ushort* xb  = (ushort*)(ws);
  ushort* wqb = (ushort*)(ws + 16777216);
  ushort* wkb = (ushort*)(ws + 25165824);
  ushort* wvb = (ushort*)(ws + 33554432);
  ushort* wob = (ushort*)(ws + 41943040);
  ushort* Qb  = (ushort*)(ws + 50331648);
  ushort* Kb  = (ushort*)(ws + 67108864);
  ushort* VTb = (ushort*)(ws + 83886080);
  ushort* AOb = xb;   // reuse: x_bf16 dead after QKV GEMMs

  // 1 dispatch: convert x + wq + wk + wv + wo into contiguous ws[0..48MB)
  cvt_all<<<24576, 256, 0, stream>>>(x, wq, wk, wv, wo, xb);

  // separate QKV GEMMs: each N=2048 keeps A+B L2-resident (R17 lesson)
  dim3 gg(32, 16);   // (M/128, N/128)
  gemm_bt<1><<<gg, 256, 0, stream>>>(xb, wqb, Qb,  4096, 2048, 2048);
  gemm_bt<1><<<gg, 256, 0, stream>>>(xb, wkb, Kb,  4096, 2048, 2048);
  gemm_bt<3><<<gg, 256, 0, stream>>>(xb, wvb, VTb, 4096, 2048, 2048);

  rope_qk<<<32768, 256, 0, stream>>>(Qb, Kb, cosb, sinb);

  flash<<<dim3(32, 16), 256, 0, stream>>>(Qb, Kb, VTb, mask, AOb);

  gemm_bt<0><<<gg, 256, 0, stream>>>(AOb, wob, d_out, 4096, 2048, 2048);
}

// Round 19
// 295.924 us; speedup vs baseline: 1.0350x; 1.0125x over previous
//
#include <hip/hip_runtime.h>

#define B_  2
#define S_  2048
#define D_  2048
#define H_  16
#define HD_ 128

typedef float  f32x4  __attribute__((ext_vector_type(4)));
typedef float  f32x16 __attribute__((ext_vector_type(16)));
typedef __bf16 bf16x8 __attribute__((ext_vector_type(8)));
typedef unsigned int u32;

__device__ __forceinline__ void gl16(const void* g, void* l) {
  __builtin_amdgcn_global_load_lds(
      (const __attribute__((address_space(1))) unsigned int*)g,
      (__attribute__((address_space(3))) unsigned int*)l, 16, 0, 0);
}

__device__ __forceinline__ ushort f2bf(float f) {
  union { float f; unsigned u; } v; v.f = f;
  unsigned r = v.u + 0x7FFFu + ((v.u >> 16) & 1u);   // RNE
  return (ushort)(r >> 16);
}
__device__ __forceinline__ float bf2f(ushort b) {
  union { unsigned u; float f; } v; v.u = ((unsigned)b) << 16;
  return v.f;
}
__device__ __forceinline__ f32x4 fzero() {
  f32x4 v; v[0] = 0.f; v[1] = 0.f; v[2] = 0.f; v[3] = 0.f; return v;
}
// raw v_exp_f32: D = 2^S0
__device__ __forceinline__ float exp2x(float x) {
  return __builtin_amdgcn_exp2f(x);
}

// ---------------- fused fp32 -> bf16 convert (all 5 inputs, 1 dispatch) ----
__global__ void cvt_all(const float* __restrict__ x,  const float* __restrict__ wq,
                        const float* __restrict__ wk, const float* __restrict__ wv,
                        const float* __restrict__ wo, ushort* __restrict__ dst)
{
  int i = blockIdx.x * blockDim.x + threadIdx.x;      // float4 index, 6291456 total
  if (i >= 6291456) return;
  const float* s;
  int t = i - 2097152;
  if (t < 0)             { s = x;  t = i; }
  else if (t < 1048576)  { s = wq; }
  else if (t < 2097152)  { s = wk; t -= 1048576; }
  else if (t < 3145728)  { s = wv; t -= 2097152; }
  else                   { s = wo; t -= 3145728; }
  float4 v = ((const float4*)s)[t];
  ((ushort4*)dst)[i] = make_ushort4(f2bf(v.x), f2bf(v.y), f2bf(v.z), f2bf(v.w));
}

// ---------------- MFMA GEMM (m97 recipe, HW-verified; 0 LDS conflicts) -----
template<int MODE>
__global__ __launch_bounds__(256, 2)
void gemm_bt(const ushort* __restrict__ A, const ushort* __restrict__ Bp,
             void* __restrict__ Cp, int M, int N, int K)
{
  __shared__ __align__(16) ushort lds[2][2][128 * 32];
  const int tid  = threadIdx.x;
  const int wave = tid >> 6, lane = tid & 63;
  const int qt = lane >> 4, ln = lane & 15;
  const int wr = wave >> 1, wc = wave & 1;
  const int bm = blockIdx.x * 128, bn = blockIdx.y * 128;

  f32x4 acc[4][4];
#pragma unroll
  for (int a = 0; a < 4; ++a)
#pragma unroll
    for (int b = 0; b < 4; ++b) acc[a][b] = fzero();

  auto stage = [&](int buf, int kt) {
#pragma unroll
    for (int it = 0; it < 2; ++it) {
      int c = it * 256 + tid;
      int row = c >> 2, ch = c & 3;
      int chs = ch ^ ((row >> 1) & 3);
      gl16(A  + (size_t)(bm + row) * K + kt + chs * 8,
           (void*)&lds[buf][0][(it * 256 + wave * 64) * 8]);
      gl16(Bp + (size_t)(bn + row) * K + kt + chs * 8,
           (void*)&lds[buf][1][(it * 256 + wave * 64) * 8]);
    }
  };

  const int nk = K >> 5;
  stage(0, 0);
  int cur = 0;
  for (int kt = 0; kt < nk; ++kt) {
    __syncthreads();                      // drains vmcnt -> buf[cur] staged
    if (kt + 1 < nk) stage(cur ^ 1, (kt + 1) << 5);
    bf16x8 af[4], bfr[4];
#pragma unroll
    for (int mf = 0; mf < 4; ++mf) {
      int row = wr * 64 + mf * 16 + ln;
      int sl = qt ^ ((row >> 1) & 3);
      af[mf] = *(const bf16x8*)&lds[cur][0][row * 32 + sl * 8];
    }
#pragma unroll
    for (int nf = 0; nf < 4; ++nf) {
      int row = wc * 64 + nf * 16 + ln;
      int sl = qt ^ ((row >> 1) & 3);
      bfr[nf] = *(const bf16x8*)&lds[cur][1][row * 32 + sl * 8];
    }
#pragma unroll
    for (int mf = 0; mf < 4; ++mf)
#pragma unroll
      for (int nf = 0; nf < 4; ++nf)
        acc[mf][nf] = __builtin_amdgcn_mfma_f32_16x16x32_bf16(
            af[mf], bfr[nf], acc[mf][nf], 0, 0, 0);
    cur ^= 1;
  }

  // epilogue: C/D layout col=lane&15, row=(lane>>4)*4+reg  [HW-verified]
#pragma unroll
  for (int mf = 0; mf < 4; ++mf)
#pragma unroll
    for (int nf = 0; nf < 4; ++nf) {
      int m0 = bm + wr * 64 + mf * 16 + qt * 4;
      int n  = bn + wc * 64 + nf * 16 + ln;
#pragma unroll
      for (int i = 0; i < 4; ++i) {
        int m = m0 + i;
        if (MODE == 0) {
          ((float*)Cp)[(size_t)m * N + n] = acc[mf][nf][i];
        } else {
          int b = m >> 11, s = m & 2047;     // m = b*S + s
          int h = n >> 7,  d = n & 127;      // n = h*HD + d
          if (MODE == 1)
            ((ushort*)Cp)[(((size_t)b * H_ + h) * S_ + s) * HD_ + d] = f2bf(acc[mf][nf][i]);
          else
            ((ushort*)Cp)[(((size_t)b * H_ + h) * HD_ + d) * S_ + s] = f2bf(acc[mf][nf][i]);
        }
      }
    }
}

// ---------------- RoPE on Q,K bf16 in (B,H,S,HD), in place ----------------
__global__ void rope_qk(ushort* __restrict__ Q, ushort* __restrict__ Kt,
                        const float* __restrict__ cs, const float* __restrict__ sn)
{
  int t = blockIdx.x * 256 + threadIdx.x;   // 2 * B*H*S * 64 threads
  int d  = t & 63;
  int rr = t >> 6;                          // 0 .. 2*B*H*S-1
  int isk = rr >> 16;                       // B*H*S = 65536
  int bhs = rr & 65535;
  int s = bhs & 2047;
  int b = bhs >> 15;
  ushort* P = isk ? Kt : Q;
  size_t ro = (size_t)bhs * HD_;
  float q0 = bf2f(P[ro + d]), q1 = bf2f(P[ro + d + 64]);
  size_t ci = ((size_t)b * S_ + s) * HD_ + d;
  float c0 = cs[ci], s0 = sn[ci], c1 = cs[ci + 64], s1 = sn[ci + 64];
  P[ro + d]      = f2bf(q0 * c0 - q1 * s0);
  P[ro + d + 64] = f2bf(q1 * c1 + q0 * s1);
}

// ---------------- flash attention: 32x32 MFMA, per-row rotation swizzle ----
// grid (B*H, S/128), 256 thr = 4 waves x 32 q-rows. K dbuf, V single buffer.
// R18 post-mortem model: LDS services b128 in 8-lane groups (8 x 16B = 128B
// = one bank sweep); each group must hit all 8 bank-quads. Reads have 8
// consecutive lanes on 8 CONSECUTIVE rows, so the slot rotation must advance
// the quad EVERY row (quad = (16*row + sl) mod 8 for K's 256B rows; = sl for
// V's 128B rows):
//   K [64 rows][16 ch]: slot = (ch + row) & 15   (quad = (ch+row) mod 8)
//   V [128 rows][8 ch]: slot = (ch + d) & 7
// Stage inverse: ch = (sl - row) & 15 / (sl - d) & 7  (rule #21; round-trip
// verified: read slot - row = wanted chunk). gemm_bt's 0-conflict pattern
// has the same all-8-quads-per-8-lane-group property.
__global__ __launch_bounds__(256, 2)
void flash(const ushort* __restrict__ Q, const ushort* __restrict__ Kk,
           const ushort* __restrict__ VT, const float* __restrict__ mask,
           ushort* __restrict__ O)
{
  __shared__ __align__(16) ushort kt_s[2][64 * 128];
  __shared__ __align__(16) ushort vt_s[128 * 64];

  const int tid = threadIdx.x;
  const int wave = tid >> 6, lane = tid & 63;
  const int ln32 = lane & 31, hi = lane >> 5;
  const int bh = blockIdx.x, b = bh >> 4, h = bh & 15;
  const size_t base  = (size_t)bh * S_ * HD_;
  const size_t baseT = (size_t)bh * HD_ * S_;
  const int q0 = blockIdx.y * 128 + wave * 32;
  const float L2E = 1.4426950408889634f;
  const float scale2 = 0.08838834764831845f * L2E;

  // Q fragments: B-operand col=lane&31=q, k = hd*16 + hi*8 + j
  bf16x8 qf[8];
  {
    const ushort* qrow = Q + base + (size_t)(q0 + ln32) * HD_;
#pragma unroll
    for (int hd = 0; hd < 8; ++hd)
      qf[hd] = *(const bf16x8*)(qrow + hd * 16 + hi * 8);
  }

  f32x16 accO[4];
#pragma unroll
  for (int dblk = 0; dblk < 4; ++dblk)
#pragma unroll
    for (int i = 0; i < 16; ++i) accO[dblk][i] = 0.f;
  float mrun = -1e30f;     // per-thread, q = ln32 (pair-synced via shfl)
  float lrun = 0.f;        // per-thread half-row partial

  auto stageK = [&](int buf, int k0) {
#pragma unroll
    for (int it = 0; it < 4; ++it) {         // 1024 chunks, 256 thr
      int c = it * 256 + tid;
      int row = c >> 4, sl = c & 15;
      int chs = (sl - row) & 15;             // inverse per-row rotation
      gl16(Kk + base + (size_t)(k0 + row) * HD_ + chs * 8,
           (void*)&kt_s[buf][(it * 256 + wave * 64) * 8]);
    }
  };
  auto stageV = [&](int k0) {
#pragma unroll
    for (int it = 0; it < 4; ++it) {         // 1024 chunks
      int c = it * 256 + tid;
      int d = c >> 3, sl = c & 7;
      int chs = (sl - d) & 7;                // inverse per-row rotation
      gl16(VT + baseT + (size_t)d * S_ + k0 + chs * 8,
           (void*)&vt_s[(it * 256 + wave * 64) * 8]);
    }
  };

  stageK(0, 0);
  stageV(0);
  int cur = 0;
  for (int k0 = 0; k0 < S_; k0 += 64) {
    __syncthreads();                         // K[cur] + V staged; prev reads done
    if (k0 + 64 < S_) stageK(cur ^ 1, k0 + 64);   // flies under compute

    // QK^T swapped: sc[kblk] = S^T[k = kblk*32+crow][q = ln32]
    f32x16 sc[2];
    __builtin_amdgcn_s_setprio(1);
#pragma unroll
    for (int kblk = 0; kblk < 2; ++kblk) {
      f32x16 a;
#pragma unroll
      for (int i = 0; i < 16; ++i) a[i] = 0.f;
      int row = kblk * 32 + ln32;
#pragma unroll
      for (int hd = 0; hd < 8; ++hd) {
        int sl = (hd * 2 + hi + row) & 15;           // per-row rotation
        bf16x8 kf = *(const bf16x8*)&kt_s[cur][row * 128 + sl * 8];
        a = __builtin_amdgcn_mfma_f32_32x32x16_bf16(kf, qf[hd], a, 0, 0, 0);
      }
      sc[kblk] = a;
    }
    __builtin_amdgcn_s_setprio(0);

    // scale + mask (log2 domain); k = kblk*32 + 8g + 4hi + j for reg=4g+j
    float sv[2][16];
#pragma unroll
    for (int kblk = 0; kblk < 2; ++kblk)
#pragma unroll
      for (int g = 0; g < 4; ++g) {
        float4 mk = *(const float4*)&mask[(size_t)b * S_ + k0 + kblk * 32 + g * 8 + hi * 4];
        sv[kblk][g * 4 + 0] = sc[kblk][g * 4 + 0] * scale2 + mk.x * L2E;
        sv[kblk][g * 4 + 1] = sc[kblk][g * 4 + 1] * scale2 + mk.y * L2E;
        sv[kblk][g * 4 + 2] = sc[kblk][g * 4 + 2] * scale2 + mk.z * L2E;
        sv[kblk][g * 4 + 3] = sc[kblk][g * 4 + 3] * scale2 + mk.w * L2E;
      }

    // row max: 31 in-thread fmax + 1 cross-lane hop (pair lane^32)
    float m = sv[0][0];
#pragma unroll
    for (int kblk = 0; kblk < 2; ++kblk)
#pragma unroll
      for (int i = 0; i < 16; ++i) m = fmaxf(m, sv[kblk][i]);
    m = fmaxf(m, __shfl_xor(m, 32));

    // defer-max rescale (THR=8, exp2 domain)
    if (__any(m > mrun + 8.f)) {
      float mn = fmaxf(mrun, m);
      float fsc = exp2x(mrun - mn);
      mrun = mn;
      lrun *= fsc;
      float fq[16];
#pragma unroll
      for (int g = 0; g < 4; ++g)
#pragma unroll
        for (int j = 0; j < 4; ++j)
          fq[g * 4 + j] = __shfl(fsc, j + 8 * g + 4 * hi);
#pragma unroll
      for (int dblk = 0; dblk < 4; ++dblk)
#pragma unroll
        for (int i = 0; i < 16; ++i) accO[dblk][i] *= fq[i];
    }

    // P = exp2(sv - mrun) -> bf16 in regs; per-thread partial sum
    float tsum = 0.f;
    ushort pb[2][16];
#pragma unroll
    for (int kblk = 0; kblk < 2; ++kblk)
#pragma unroll
      for (int i = 0; i < 16; ++i) {
        float p = exp2x(sv[kblk][i] - mrun);
        __bf16 pq = (__bf16)p;               // HW cvt, RNE
        union { __bf16 b; ushort s; } cc; cc.b = pq;
        pb[kblk][i] = cc.s;
        tsum += (float)pq;                   // sum QUANTIZED P -> exact norm
      }
    lrun += tsum;

    // assemble PV A-frags in-register (2 shfl_xor(32) per frag pair)
    bf16x8 pa[4];
#pragma unroll
    for (int kblk = 0; kblk < 2; ++kblk) {
      u32 pk0[4], pk1[4];
#pragma unroll
      for (int t = 0; t < 4; ++t) {
        pk0[t] = (u32)pb[kblk][4 * t]     | ((u32)pb[kblk][4 * t + 1] << 16);
        pk1[t] = (u32)pb[kblk][4 * t + 2] | ((u32)pb[kblk][4 * t + 3] << 16);
      }
#pragma unroll
      for (int c = 0; c < 2; ++c) {
        u32 a0 = pk0[2 * c],     a1 = pk1[2 * c];       // t' = 2c
        u32 b0 = pk0[2 * c + 1], b1 = pk1[2 * c + 1];   // t' = 2c+1
        u32 s0 = hi ? a0 : b0,   s1 = hi ? a1 : b1;     // partner needs t'=(1-hi)+2c
        u32 r0 = (u32)__shfl_xor((int)s0, 32);
        u32 r1 = (u32)__shfl_xor((int)s1, 32);
        u32 o0 = hi ? b0 : a0,   o1 = hi ? b1 : a1;     // own t' = hi+2c
        u32 w[4];
        w[0] = hi ? r0 : o0;  w[1] = hi ? r1 : o1;      // quad(t',0)
        w[2] = hi ? o0 : r0;  w[3] = hi ? o1 : r1;      // quad(t',1)
        pa[kblk * 2 + c] = *(bf16x8*)w;
      }
    }

    // PV: accO[q 32][d 128] += P * V
    __builtin_amdgcn_s_setprio(1);
#pragma unroll
    for (int kk = 0; kk < 4; ++kk)
#pragma unroll
      for (int dblk = 0; dblk < 4; ++dblk) {
        int d = dblk * 32 + ln32;
        int sl = (kk * 2 + hi + d) & 7;                 // per-row rotation
        bf16x8 vf = *(const bf16x8*)&vt_s[d * 64 + sl * 8];
        accO[dblk] = __builtin_amdgcn_mfma_f32_32x32x16_bf16(pa[kk], vf, accO[dblk], 0, 0, 0);
      }
    __builtin_amdgcn_s_setprio(0);

    __syncthreads();                         // all waves done reading V
    if (k0 + 64 < S_) stageV(k0 + 64);       // covered by co-resident block
    cur ^= 1;
  }

  // epilogue: pair-reduce lrun, fetch inv per accO row, write O (B,S,D) bf16
  lrun += __shfl_xor(lrun, 32);
  float inv_own = 1.f / lrun;
  float invv[16];
#pragma unroll
  for (int g = 0; g < 4; ++g)
#pragma unroll
    for (int j = 0; j < 4; ++j)
      invv[g * 4 + j] = __shfl(inv_own, j + 8 * g + 4 * hi);
#pragma unroll
  for (int dblk = 0; dblk < 4; ++dblk)
#pragma unroll
    for (int g = 0; g < 4; ++g)
#pragma unroll
      for (int j = 0; j < 4; ++j) {
        int q = j + 8 * g + 4 * hi;
        size_t idx = ((size_t)b * S_ + q0 + q) * D_ + h * HD_ + dblk * 32 + ln32;
        O[idx] = f2bf(accO[dblk][g * 4 + j] * invv[g * 4 + j]);
      }
}

// ---------------- launcher ----------------
extern "C" void kernel_launch(void* const* d_in, const int* in_sizes, int n_in,
                              void* d_out, int out_size, void* d_ws, size_t ws_size,
                              hipStream_t stream)
{
  if (n_in != 8) return;
  if (in_sizes[0] != 8388608) return;       // x  (B,S,D)
  if (in_sizes[3] != 4096)    return;       // mask (B,S)
  if (out_size != 8388608) return;
  if (ws_size < (size_t)96 * 1024 * 1024) return;

  const float* x    = (const float*)d_in[0];
  const float* cosb = (const float*)d_in[1];
  const float* sinb = (const float*)d_in[2];
  const float* mask = (const float*)d_in[3];
  const float* wq   = (const float*)d_in[4];
  const float* wk   = (const float*)d_in[5];
  const float* wv   = (const float*)d_in[6];
  const float* wo   = (const float*)d_in[7];

  char* ws = (char*)d_ws;
  // layout (MB): xb 0..16 | wqb 16..24 | wkb 24..32 | wvb 32..40 | wob 40..48 |
  //              Qb 48..64 | Kb 64..80 | VTb 80..96
  ushort* xb  = (ushort*)(ws);
  ushort* wqb = (ushort*)(ws + 16777216);
  ushort* wkb = (ushort*)(ws + 25165824);
  ushort* wvb = (ushort*)(ws + 33554432);
  ushort* wob = (ushort*)(ws + 41943040);
  ushort* Qb  = (ushort*)(ws + 50331648);
  ushort* Kb  = (ushort*)(ws + 67108864);
  ushort* VTb = (ushort*)(ws + 83886080);
  ushort* AOb = xb;   // reuse: x_bf16 dead after QKV GEMMs

  // 1 dispatch: convert x + wq + wk + wv + wo into contiguous ws[0..48MB)
  cvt_all<<<24576, 256, 0, stream>>>(x, wq, wk, wv, wo, xb);

  // separate QKV GEMMs: each N=2048 keeps A+B L2-resident (R17 lesson)
  dim3 gg(32, 16);   // (M/128, N/128)
  gemm_bt<1><<<gg, 256, 0, stream>>>(xb, wqb, Qb,  4096, 2048, 2048);
  gemm_bt<1><<<gg, 256, 0, stream>>>(xb, wkb, Kb,  4096, 2048, 2048);
  gemm_bt<3><<<gg, 256, 0, stream>>>(xb, wvb, VTb, 4096, 2048, 2048);

  rope_qk<<<32768, 256, 0, stream>>>(Qb, Kb, cosb, sinb);

  flash<<<dim3(32, 16), 256, 0, stream>>>(Qb, Kb, VTb, mask, AOb);

  gemm_bt<0><<<gg, 256, 0, stream>>>(AOb, wob, d_out, 4096, 2048, 2048);
}